// Round 1
// baseline (5451.776 us; speedup 1.0000x reference)
//
#include <hip/hip_runtime.h>

// SpMM: out[src[e], :] += att[e] * X[dst[e], :]
// edges: int32 (2, E) row-major -> src = edges[0..E), dst = edges[E..2E)
// X: (N, 128) fp32, out: (N, 128) fp32

constexpr int D_FEAT = 128;
constexpr int LANES_PER_EDGE = 32;   // 128 floats / float4 = 32 lanes

__global__ __launch_bounds__(256) void spmm_edge_atomic(
    const int* __restrict__ src,
    const int* __restrict__ dst,
    const float* __restrict__ att,
    const float* __restrict__ X,
    float* __restrict__ out,
    int E)
{
    const int group   = (int)((blockIdx.x * blockDim.x + threadIdx.x) >> 5);
    const int lane    = threadIdx.x & (LANES_PER_EDGE - 1);
    const int nGroups = (int)((gridDim.x * blockDim.x) >> 5);

    for (int e = group; e < E; e += nGroups) {
        const int   s = src[e];
        const int   d = dst[e];
        const float a = att[e];

        const float4 v = ((const float4*)(X + (size_t)d * D_FEAT))[lane];

        float* o = out + (size_t)s * D_FEAT + (size_t)lane * 4;
        unsafeAtomicAdd(o + 0, a * v.x);
        unsafeAtomicAdd(o + 1, a * v.y);
        unsafeAtomicAdd(o + 2, a * v.z);
        unsafeAtomicAdd(o + 3, a * v.w);
    }
}

extern "C" void kernel_launch(void* const* d_in, const int* in_sizes, int n_in,
                              void* d_out, int out_size, void* d_ws, size_t ws_size,
                              hipStream_t stream) {
    const int*   edges = (const int*)d_in[0];      // (2, E) int32
    const float* att   = (const float*)d_in[1];    // (E,)
    const float* X     = (const float*)d_in[3];    // (N, 128)
    float*       out   = (float*)d_out;            // (N, 128)

    const int E = in_sizes[1];                     // attentions length = n edges
    const int* src = edges;
    const int* dst = edges + E;

    // Harness re-poisons d_out with 0xAA before every launch — zero it.
    hipMemsetAsync(d_out, 0, (size_t)out_size * sizeof(float), stream);

    // 8 edges per 256-thread block
    const int edgesPerBlock = 256 / LANES_PER_EDGE;
    const int grid = (E + edgesPerBlock - 1) / edgesPerBlock;

    spmm_edge_atomic<<<grid, 256, 0, stream>>>(src, dst, att, X, out, E);
}

// Round 2
// 947.384 us; speedup vs baseline: 5.7546x; 5.7546x over previous
//
#include <hip/hip_runtime.h>

typedef unsigned int u32;

// SpMM: out[src[e], :] += att[e] * X[dst[e], :]
// Strategy: build CSR by src on-device (histogram -> scan -> scatter),
// then per-row register-accumulate gather (zero float atomics).

constexpr int D_FEAT = 128;
constexpr int N_NODES_C = 100000;   // fixed by problem (N arrives as device scalar)

// ---------- Phase A: histogram of src ----------
__global__ __launch_bounds__(256) void hist_kernel(const int* __restrict__ src,
                                                   u32* __restrict__ cnt, int E) {
    int i = blockIdx.x * blockDim.x + threadIdx.x;
    if (i < E) atomicAdd(&cnt[src[i]], 1u);
}

// ---------- Phase B: single-block exclusive scan (N up to 1024*chunk) ----------
__global__ __launch_bounds__(1024) void scan_kernel(const u32* __restrict__ cnt,
                                                    u32* __restrict__ row_ptr,
                                                    u32* __restrict__ cursor, int N) {
    __shared__ u32 sdata[1024];
    const int tid = threadIdx.x;
    const int C = (N + 1023) / 1024;
    const int b = tid * C;

    u32 total = 0;
    for (int j = 0; j < C; ++j) {
        int idx = b + j;
        if (idx < N) total += cnt[idx];
    }
    sdata[tid] = total;
    __syncthreads();
    for (int ofs = 1; ofs < 1024; ofs <<= 1) {
        u32 v = (tid >= ofs) ? sdata[tid - ofs] : 0u;
        __syncthreads();
        sdata[tid] += v;
        __syncthreads();
    }
    u32 run = sdata[tid] - total;   // exclusive prefix of this thread's chunk
    for (int j = 0; j < C; ++j) {
        int idx = b + j;
        if (idx < N) {
            u32 c = cnt[idx];
            row_ptr[idx] = run;
            cursor[idx]  = run;
            run += c;
        }
    }
    if (tid == 1023) row_ptr[N] = sdata[1023];
}

// ---------- Phase C: scatter (dst, att) into CSR order ----------
__global__ __launch_bounds__(256) void scatter_kernel(const int* __restrict__ src,
                                                      const int* __restrict__ dst,
                                                      const float* __restrict__ att,
                                                      u32* __restrict__ cursor,
                                                      int2* __restrict__ epack, int E) {
    int i = blockIdx.x * blockDim.x + threadIdx.x;
    if (i < E) {
        int s = src[i];
        u32 pos = atomicAdd(&cursor[s], 1u);
        epack[pos] = make_int2(dst[i], __float_as_int(att[i]));
    }
}

// ---------- Phase D: per-row gather-accumulate ----------
__global__ __launch_bounds__(256) void gather_kernel(const u32* __restrict__ row_ptr,
                                                     const int2* __restrict__ epack,
                                                     const float* __restrict__ X,
                                                     float* __restrict__ out, int N) {
    const int row  = (int)((blockIdx.x * blockDim.x + threadIdx.x) >> 5);
    const int lane = threadIdx.x & 31;
    if (row >= N) return;

    const u32 s = row_ptr[row];
    const u32 e = row_ptr[row + 1];
    const float4* __restrict__ X4 = (const float4*)X;

    float4 acc = make_float4(0.f, 0.f, 0.f, 0.f);
    u32 k = s;
    // unroll-by-2 for a little ILP on the dependent broadcast->gather chain
    for (; k + 2 <= e; k += 2) {
        int2 p0 = epack[k];
        int2 p1 = epack[k + 1];
        float4 v0 = X4[(size_t)p0.x * 32 + lane];
        float4 v1 = X4[(size_t)p1.x * 32 + lane];
        float a0 = __int_as_float(p0.y);
        float a1 = __int_as_float(p1.y);
        acc.x = fmaf(a0, v0.x, acc.x); acc.y = fmaf(a0, v0.y, acc.y);
        acc.z = fmaf(a0, v0.z, acc.z); acc.w = fmaf(a0, v0.w, acc.w);
        acc.x = fmaf(a1, v1.x, acc.x); acc.y = fmaf(a1, v1.y, acc.y);
        acc.z = fmaf(a1, v1.z, acc.z); acc.w = fmaf(a1, v1.w, acc.w);
    }
    for (; k < e; ++k) {
        int2 p = epack[k];
        float4 v = X4[(size_t)p.x * 32 + lane];
        float a = __int_as_float(p.y);
        acc.x = fmaf(a, v.x, acc.x); acc.y = fmaf(a, v.y, acc.y);
        acc.z = fmaf(a, v.z, acc.z); acc.w = fmaf(a, v.w, acc.w);
    }
    ((float4*)out)[(size_t)row * 32 + lane] = acc;
}

// ---------- Fallback (round-1): edge-parallel fp atomics ----------
__global__ __launch_bounds__(256) void spmm_edge_atomic(
    const int* __restrict__ src, const int* __restrict__ dst,
    const float* __restrict__ att, const float* __restrict__ X,
    float* __restrict__ out, int E)
{
    const int group = (int)((blockIdx.x * blockDim.x + threadIdx.x) >> 5);
    const int lane  = threadIdx.x & 31;
    const int nGroups = (int)((gridDim.x * blockDim.x) >> 5);
    for (int e = group; e < E; e += nGroups) {
        const int s = src[e], d = dst[e];
        const float a = att[e];
        const float4 v = ((const float4*)(X + (size_t)d * D_FEAT))[lane];
        float* o = out + (size_t)s * D_FEAT + (size_t)lane * 4;
        unsafeAtomicAdd(o + 0, a * v.x);
        unsafeAtomicAdd(o + 1, a * v.y);
        unsafeAtomicAdd(o + 2, a * v.z);
        unsafeAtomicAdd(o + 3, a * v.w);
    }
}

static inline size_t align16(size_t x) { return (x + 15) & ~(size_t)15; }

extern "C" void kernel_launch(void* const* d_in, const int* in_sizes, int n_in,
                              void* d_out, int out_size, void* d_ws, size_t ws_size,
                              hipStream_t stream) {
    const int*   edges = (const int*)d_in[0];   // (2, E) int32
    const float* att   = (const float*)d_in[1]; // (E,)
    const float* X     = (const float*)d_in[3]; // (N, 128)
    float*       out   = (float*)d_out;

    const int E = in_sizes[1];
    const int N = N_NODES_C;
    const int* src = edges;
    const int* dst = edges + E;

    // Workspace layout
    size_t o_cnt    = 0;
    size_t o_rowptr = o_cnt + (size_t)N * 4;
    size_t o_cursor = o_rowptr + ((size_t)N + 1) * 4;
    size_t o_epack  = align16(o_cursor + (size_t)N * 4);
    size_t need     = o_epack + (size_t)E * 8;

    if (ws_size < need) {
        // Fallback: atomic scatter (round-1 behavior)
        hipMemsetAsync(d_out, 0, (size_t)out_size * sizeof(float), stream);
        const int grid = (E + 7) / 8;
        spmm_edge_atomic<<<grid, 256, 0, stream>>>(src, dst, att, X, out, E);
        return;
    }

    char* ws = (char*)d_ws;
    u32*  cnt     = (u32*)(ws + o_cnt);
    u32*  row_ptr = (u32*)(ws + o_rowptr);
    u32*  cursor  = (u32*)(ws + o_cursor);
    int2* epack   = (int2*)(ws + o_epack);

    hipMemsetAsync(cnt, 0, (size_t)N * 4, stream);

    const int gridE = (E + 255) / 256;
    hist_kernel<<<gridE, 256, 0, stream>>>(src, cnt, E);
    scan_kernel<<<1, 1024, 0, stream>>>(cnt, row_ptr, cursor, N);
    scatter_kernel<<<gridE, 256, 0, stream>>>(src, dst, att, cursor, epack, E);

    const int gridN = (N * 32 + 255) / 256;
    gather_kernel<<<gridN, 256, 0, stream>>>(row_ptr, epack, X, out, N);
}